// Round 10
// baseline (16849.828 us; speedup 1.0000x reference)
//
#include <hip/hip_runtime.h>
#include <hip/hip_cooperative_groups.h>

namespace cg = cooperative_groups;

#define HIDDEN   2048
#define VOCAB    7
#define STEPS    1024
#define NWB      256            // worker blocks
#define NTHREADS 512            // 8 waves per block
#define WPB      8              // waves (= hidden units) per worker block
#define LFAN     16
#define NLEAF    (NWB / LFAN)   // 16 leaves, root fan-in 16
#define NBLOCKS  (NWB + 1)      // + dedicated logits block

typedef unsigned long long u64;

// Cross-block state in device globals.
__device__ __align__(256) float g_h[3][HIDDEN];    // h triple-buffer
__device__ __align__(256) int   g_c0[NLEAF * 32];  // leaf counters, 128B apart
__device__ __align__(256) int   g_c2[32];          // root counter
__device__ __align__(256) int   g_hgen[8 * 32];    // h-generation replicas
__device__ __align__(256) u64   g_xip[8 * 16];     // (gen<<32|xi) replicas
// fallback-only state
__device__ float g_c[HIDDEN];
__device__ float g_partfb[512 * VOCAB];
__device__ int   g_xi;

__device__ __forceinline__ float sigm(float x) { return 1.0f / (1.0f + expf(-x)); }

// ALL hot-path cross-block ops are RELAXED agent-scope (sc1 point ops at the
// MALL — no cache-maintenance storm; validated r6, 11.6x). Ordering: vmcnt
// drain before arrive-RMW + real-time order at the single coherence point.
#define LOAD_AG(p)     __hip_atomic_load((p), __ATOMIC_RELAXED, __HIP_MEMORY_SCOPE_AGENT)
#define STORE_AG(p, v) __hip_atomic_store((p), (v), __ATOMIC_RELAXED, __HIP_MEMORY_SCOPE_AGENT)
#define RMW_ADD_AG(p)  __hip_atomic_fetch_add((p), 1, __ATOMIC_RELAXED, __HIP_MEMORY_SCOPE_AGENT)
#define VM_DRAIN()     asm volatile("s_waitcnt vmcnt(0)" ::: "memory")
#define C_FENCE()      asm volatile("" ::: "memory")

// Load h[4m..4m+3] as two 8B relaxed agent loads (bypass stale L1/L2).
__device__ __forceinline__ float4 h_pair(const u64* h8, int m) {
    u64 lo = LOAD_AG((u64*)&h8[2 * m]);
    u64 hi = LOAD_AG((u64*)&h8[2 * m + 1]);
    float4 r;
    r.x = __uint_as_float((unsigned)lo);
    r.y = __uint_as_float((unsigned)(lo >> 32));
    r.z = __uint_as_float((unsigned)hi);
    r.w = __uint_as_float((unsigned)(hi >> 32));
    return r;
}

// Register-array select with compile-time indices only (no scratch).
__device__ __forceinline__ float sel7(const float w[VOCAB], int xi) {
    float r = w[0];
    #pragma unroll
    for (int v = 1; v < VOCAB; ++v) r = (xi == v) ? w[v] : r;
    return r;
}

// ---------------- cooperative single-dispatch kernel ----------------
__global__ __launch_bounds__(NTHREADS, 2)
void coop_kernel(const float* __restrict__ h0,  const float* __restrict__ c0,
                 const float* __restrict__ W_ih, const float* __restrict__ W_hh,
                 const float* __restrict__ b_ih, const float* __restrict__ b_hh,
                 const float* __restrict__ W_out, const float* __restrict__ b_out,
                 float* __restrict__ out)
{
    cg::grid_group grid = cg::this_grid();
    const int tid  = threadIdx.x;
    const int bx   = blockIdx.x;
    const int gid  = bx * NTHREADS + tid;
    const int lane = tid & 63;
    const int wib  = tid >> 6;

    __shared__ float s_lg[2][8];   // logits block only (parity-indexed)

    // ---- per-launch init (replay-safe) ----
    if (gid < HIDDEN) STORE_AG(&g_h[0][gid], h0[gid]);
    if (bx == 0) {
        if (tid < NLEAF) STORE_AG(&g_c0[tid * 32], 0);
        if (tid == 0)    STORE_AG(&g_c2[0], 0);
        if (tid < 8)     { STORE_AG(&g_hgen[tid * 32], 0); STORE_AG(&g_xip[tid * 16], (u64)0); }
    }

    grid.sync();   // ONE cooperative barrier, init only

    if (bx < NWB) {
        // ================= worker block: 8 waves, 1 hidden unit each =================
        const int j    = bx * WPB + wib;   // hidden unit 0..2047
        const int leaf = bx >> 4;          // 0..15
        const int rep  = bx >> 5;          // replica 0..7

        const float4* Wr0 = (const float4*)(W_hh + (size_t)j * HIDDEN);
        const float4* Wr1 = (const float4*)(W_hh + (size_t)(j + HIDDEN) * HIDDEN);
        const float4* Wr2 = (const float4*)(W_hh + (size_t)(j + 2 * HIDDEN) * HIDDEN);
        const float4* Wr3 = (const float4*)(W_hh + (size_t)(j + 3 * HIDDEN) * HIDDEN);

        float bsum0 = 0.f, bsum1 = 0.f, bsum2 = 0.f, bsum3 = 0.f;
        float cv = 0.f, h_fin = 0.f;
        float wih0[VOCAB], wih1[VOCAB], wih2[VOCAB], wih3[VOCAB];
        if (lane == 0) {
            bsum0 = b_ih[j]              + b_hh[j];
            bsum1 = b_ih[j + HIDDEN]     + b_hh[j + HIDDEN];
            bsum2 = b_ih[j + 2 * HIDDEN] + b_hh[j + 2 * HIDDEN];
            bsum3 = b_ih[j + 3 * HIDDEN] + b_hh[j + 3 * HIDDEN];
            cv = c0[j];    // c lives in a register all 1024 steps
            #pragma unroll
            for (int v = 0; v < VOCAB; ++v) {
                wih0[v] = W_ih[(size_t)j * VOCAB + v];
                wih1[v] = W_ih[(size_t)(j + HIDDEN) * VOCAB + v];
                wih2[v] = W_ih[(size_t)(j + 2 * HIDDEN) * VOCAB + v];
                wih3[v] = W_ih[(size_t)(j + 3 * HIDDEN) * VOCAB + v];
            }
        }

        int rb = 0, wbuf = 1;   // h buffer rotation (mod 3)

        for (int t = 0; t < STEPS; ++t) {
            // wave-wide spin: h(t) ready? (all lanes load same addr -> 1 request)
            int cur = LOAD_AG(&g_hgen[rep * 32]);
            while (cur < t) { __builtin_amdgcn_s_sleep(2); cur = LOAD_AG(&g_hgen[rep * 32]); }
            C_FENCE();

            const u64* h8 = (const u64*)g_h[rb];
            float4 hreg[8];
            #pragma unroll
            for (int it = 0; it < 8; ++it) hreg[it] = h_pair(h8, it * 64 + lane);

            float a0 = 0.f, a1 = 0.f, a2 = 0.f, a3 = 0.f;
            #pragma unroll
            for (int it = 0; it < 8; ++it) {
                const float4 hv = hreg[it];
                const float4 w0 = Wr0[it * 64 + lane];
                const float4 w1 = Wr1[it * 64 + lane];
                const float4 w2 = Wr2[it * 64 + lane];
                const float4 w3 = Wr3[it * 64 + lane];
                a0 += w0.x * hv.x + w0.y * hv.y + w0.z * hv.z + w0.w * hv.w;
                a1 += w1.x * hv.x + w1.y * hv.y + w1.z * hv.z + w1.w * hv.w;
                a2 += w2.x * hv.x + w2.y * hv.y + w2.z * hv.z + w2.w * hv.w;
                a3 += w3.x * hv.x + w3.y * hv.y + w3.z * hv.z + w3.w * hv.w;
            }
            #pragma unroll
            for (int off = 32; off > 0; off >>= 1) {
                a0 += __shfl_down(a0, off, 64);
                a1 += __shfl_down(a1, off, 64);
                a2 += __shfl_down(a2, off, 64);
                a3 += __shfl_down(a3, off, 64);
            }

            // xi(t): published by the logits block with gen == t (t>=1).
            // Normally long ready (logits ran concurrently with our GEMV).
            int xi = VOCAB - 1;   // SOS for t == 0
            if (t > 0) {
                u64 px = LOAD_AG(&g_xip[rep * 16]);
                while ((int)(px >> 32) < t) { __builtin_amdgcn_s_sleep(1); px = LOAD_AG(&g_xip[rep * 16]); }
                xi = (int)(unsigned)px;
            }
            C_FENCE();

            if (lane == 0) {
                const float gi = a0 + bsum0 + sel7(wih0, xi);
                const float gf = a1 + bsum1 + sel7(wih1, xi);
                const float gg = a2 + bsum2 + sel7(wih2, xi);
                const float go = a3 + bsum3 + sel7(wih3, xi);
                cv  = sigm(gf) * cv + sigm(gi) * tanhf(gg);
                const float h2v = sigm(go) * tanhf(cv);
                h_fin = h2v;
                STORE_AG(&g_h[wbuf][j], h2v);   // relaxed sc1, lands at MALL
            }
            VM_DRAIN();        // this wave's h store at MALL
            __syncthreads();   // all 8 waves drained

            // 2-level counting tree (no data), tid 0 only
            if (tid == 0) {
                const int o0 = RMW_ADD_AG(&g_c0[leaf * 32]);
                if (o0 == (t + 1) * LFAN - 1) {              // leaf boss
                    const int o2 = RMW_ADD_AG(&g_c2[0]);
                    if (o2 == (t + 1) * NLEAF - 1) {         // root boss
                        #pragma unroll
                        for (int r = 0; r < 8; ++r) STORE_AG(&g_hgen[r * 32], t + 1);
                    }
                }
            }

            rb = wbuf;
            wbuf = (wbuf + 1 == 3) ? 0 : wbuf + 1;
        }

        // final state straight from registers
        if (lane == 0) {
            out[STEPS * VOCAB + j]          = h_fin;
            out[STEPS * VOCAB + HIDDEN + j] = cv;
        }
    } else {
        // ================= dedicated logits block =================
        // For s = 1..1024: wait h(s), compute logits = W_out h(s) + b_out,
        // write out[s-1], publish (s<<32 | argmax). Runs concurrently with
        // the workers' step-s GEMV — off the barrier-critical path.
        const int v = wib;   // vocab row 0..6 (wave 7 idles through barriers)
        float bov[VOCAB];
        #pragma unroll
        for (int q = 0; q < VOCAB; ++q) bov[q] = b_out[q];
        const float4* Wo = (const float4*)(W_out + (size_t)(v < VOCAB ? v : 0) * HIDDEN);

        for (int s = 1; s <= STEPS; ++s) {
            int cur = LOAD_AG(&g_hgen[7 * 32]);
            while (cur < s) { __builtin_amdgcn_s_sleep(1); cur = LOAD_AG(&g_hgen[7 * 32]); }
            C_FENCE();

            if (v < VOCAB) {
                const u64* h8 = (const u64*)g_h[s % 3];
                float acc = 0.f;
                #pragma unroll
                for (int it = 0; it < 8; ++it) {
                    const float4 hv = h_pair(h8, it * 64 + lane);
                    const float4 w  = Wo[it * 64 + lane];
                    acc += w.x * hv.x + w.y * hv.y + w.z * hv.z + w.w * hv.w;
                }
                #pragma unroll
                for (int off = 32; off > 0; off >>= 1) acc += __shfl_down(acc, off, 64);
                if (lane == 0) s_lg[s & 1][v] = acc;
            }
            __syncthreads();   // one barrier/step; parity LDS slot prevents WAR

            if (tid == 0) {
                float l[VOCAB];
                float mx = -1e30f;
                #pragma unroll
                for (int q = 0; q < VOCAB; ++q) { l[q] = s_lg[s & 1][q] + bov[q]; mx = fmaxf(mx, l[q]); }
                float se = 0.0f;
                #pragma unroll
                for (int q = 0; q < VOCAB; ++q) se += expf(l[q] - mx);
                const float lse = mx + logf(se);
                int am = 0; float best = l[0];
                #pragma unroll
                for (int q = 1; q < VOCAB; ++q) if (l[q] > best) { best = l[q]; am = q; }
                #pragma unroll
                for (int q = 0; q < VOCAB; ++q) out[(s - 1) * VOCAB + q] = l[q] - lse;
                const u64 val = ((u64)(unsigned)s << 32) | (u64)(unsigned)am;
                #pragma unroll
                for (int r = 0; r < 8; ++r) STORE_AG(&g_xip[r * 16], val);
            }
        }
    }
}

// ---------------- fallback: sequential per-step kernels (proven, old geometry) ----------------
__global__ __launch_bounds__(256)
void fb_init(const float* __restrict__ h0, const float* __restrict__ c0) {
    int gid = blockIdx.x * 256 + threadIdx.x;
    if (gid < HIDDEN) { g_h[0][gid] = h0[gid]; g_c[gid] = c0[gid]; }
    if (gid == 0) g_xi = VOCAB - 1;
}

__global__ __launch_bounds__(256, 2)
void fb_step(const float* __restrict__ W_ih, const float* __restrict__ W_hh,
             const float* __restrict__ b_ih, const float* __restrict__ b_hh,
             const float* __restrict__ W_out, int t)
{
    const int tid  = threadIdx.x;
    const int lane = tid & 63;
    const int wib  = tid >> 6;
    const int j    = blockIdx.x * 4 + wib;

    __shared__ float s_part[4][VOCAB];

    const float4* h4 = (const float4*)g_h[t & 1];
    const float4* Wr0 = (const float4*)(W_hh + (size_t)j * HIDDEN);
    const float4* Wr1 = (const float4*)(W_hh + (size_t)(j + HIDDEN) * HIDDEN);
    const float4* Wr2 = (const float4*)(W_hh + (size_t)(j + 2 * HIDDEN) * HIDDEN);
    const float4* Wr3 = (const float4*)(W_hh + (size_t)(j + 3 * HIDDEN) * HIDDEN);

    float a0 = 0.f, a1 = 0.f, a2 = 0.f, a3 = 0.f;
    #pragma unroll
    for (int it = 0; it < 8; ++it) {
        const float4 hv = h4[it * 64 + lane];
        const float4 w0 = Wr0[it * 64 + lane];
        const float4 w1 = Wr1[it * 64 + lane];
        const float4 w2 = Wr2[it * 64 + lane];
        const float4 w3 = Wr3[it * 64 + lane];
        a0 += w0.x * hv.x + w0.y * hv.y + w0.z * hv.z + w0.w * hv.w;
        a1 += w1.x * hv.x + w1.y * hv.y + w1.z * hv.z + w1.w * hv.w;
        a2 += w2.x * hv.x + w2.y * hv.y + w2.z * hv.z + w2.w * hv.w;
        a3 += w3.x * hv.x + w3.y * hv.y + w3.z * hv.z + w3.w * hv.w;
    }
    #pragma unroll
    for (int off = 32; off > 0; off >>= 1) {
        a0 += __shfl_down(a0, off, 64);
        a1 += __shfl_down(a1, off, 64);
        a2 += __shfl_down(a2, off, 64);
        a3 += __shfl_down(a3, off, 64);
    }

    float h2v = 0.0f;
    if (lane == 0) {
        const int xi = g_xi;
        const float gi = a0 + b_ih[j] + b_hh[j] + W_ih[j * VOCAB + xi];
        const float gf = a1 + b_ih[j + HIDDEN] + b_hh[j + HIDDEN] + W_ih[(j + HIDDEN) * VOCAB + xi];
        const float gg = a2 + b_ih[j + 2 * HIDDEN] + b_hh[j + 2 * HIDDEN] + W_ih[(j + 2 * HIDDEN) * VOCAB + xi];
        const float go = a3 + b_ih[j + 3 * HIDDEN] + b_hh[j + 3 * HIDDEN] + W_ih[(j + 3 * HIDDEN) * VOCAB + xi];
        const float cv = sigm(gf) * g_c[j] + sigm(gi) * tanhf(gg);
        h2v = sigm(go) * tanhf(cv);
        g_c[j] = cv;
        g_h[(t + 1) & 1][j] = h2v;
    }
    h2v = __shfl(h2v, 0, 64);

    const float wout = (lane < VOCAB) ? W_out[lane * HIDDEN + j] : 0.0f;
    if (lane < VOCAB) s_part[wib][lane] = h2v * wout;
    __syncthreads();
    if (tid < VOCAB)
        g_partfb[blockIdx.x * VOCAB + tid] =
            s_part[0][tid] + s_part[1][tid] + s_part[2][tid] + s_part[3][tid];
}

__global__ void fb_logits(const float* __restrict__ b_out, float* __restrict__ out, int t) {
    const int lane = threadIdx.x;   // 64 threads
    float lg[VOCAB];
    #pragma unroll
    for (int v = 0; v < VOCAB; ++v) {
        float s = 0.0f;
        for (int i = lane; i < 512; i += 64) s += g_partfb[i * VOCAB + v];
        #pragma unroll
        for (int off = 32; off > 0; off >>= 1) s += __shfl_down(s, off, 64);
        lg[v] = s;
    }
    if (lane == 0) {
        float l[VOCAB];
        float mx = -1e30f;
        #pragma unroll
        for (int v = 0; v < VOCAB; ++v) { l[v] = lg[v] + b_out[v]; mx = fmaxf(mx, l[v]); }
        float se = 0.0f;
        #pragma unroll
        for (int v = 0; v < VOCAB; ++v) se += expf(l[v] - mx);
        const float lse = mx + logf(se);
        int am = 0; float best = l[0];
        #pragma unroll
        for (int v = 1; v < VOCAB; ++v) if (l[v] > best) { best = l[v]; am = v; }
        #pragma unroll
        for (int v = 0; v < VOCAB; ++v) out[t * VOCAB + v] = l[v] - lse;
        g_xi = am;
    }
}

__global__ __launch_bounds__(256)
void fb_fin(float* __restrict__ out) {
    int gid = blockIdx.x * 256 + threadIdx.x;
    if (gid < HIDDEN) {
        out[STEPS * VOCAB + gid]          = g_h[0][gid];
        out[STEPS * VOCAB + HIDDEN + gid] = g_c[gid];
    }
}

extern "C" void kernel_launch(void* const* d_in, const int* in_sizes, int n_in,
                              void* d_out, int out_size, void* d_ws, size_t ws_size,
                              hipStream_t stream)
{
    const float* h0    = (const float*)d_in[0];
    const float* c0    = (const float*)d_in[1];
    const float* W_ih  = (const float*)d_in[2];
    const float* W_hh  = (const float*)d_in[3];
    const float* b_ih  = (const float*)d_in[4];
    const float* b_hh  = (const float*)d_in[5];
    const float* W_out = (const float*)d_in[6];
    const float* b_out = (const float*)d_in[7];
    float* out = (float*)d_out;

    void* args[] = { &h0, &c0, &W_ih, &W_hh, &b_ih, &b_hh, &W_out, &b_out, &out };
    hipError_t e = hipLaunchCooperativeKernel((void*)coop_kernel,
                                              dim3(NBLOCKS), dim3(NTHREADS), args, 0, stream);
    if (e != hipSuccess) {
        fb_init<<<HIDDEN / 256, 256, 0, stream>>>(h0, c0);
        for (int t = 0; t < STEPS; ++t) {
            fb_step<<<512, 256, 0, stream>>>(W_ih, W_hh, b_ih, b_hh, W_out, t);
            fb_logits<<<1, 64, 0, stream>>>(b_out, out, t);
        }
        fb_fin<<<HIDDEN / 256, 256, 0, stream>>>(out);
    }
}

// Round 11
// 13554.718 us; speedup vs baseline: 1.2431x; 1.2431x over previous
//
#include <hip/hip_runtime.h>
#include <hip/hip_cooperative_groups.h>

namespace cg = cooperative_groups;

#define HIDDEN   2048
#define VOCAB    7
#define STEPS    1024
#define NBLOCKS  512
#define NTHREADS 256
#define NWAVES   (NTHREADS / 64)
#define FAN      8
#define NLEAF    (NBLOCKS / FAN)   // 64 leaves; root fan-in 64

typedef unsigned long long u64;

// Cross-block state in device globals.
__device__ __align__(256) float g_h[3][HIDDEN];      // h triple-buffer
__device__ __align__(256) float g_pt[VOCAB][NBLOCKS]; // TRANSPOSED partials: row v = 2KB
__device__ __align__(256) int   g_c0[NLEAF * 32];    // leaf counters, 128B apart
__device__ __align__(256) int   g_c2[32];            // root counter
__device__ __align__(256) int   g_hgen[8 * 32];      // h-generation replicas
__device__ __align__(256) u64   g_xip[8 * 16];       // (gen<<32|xi) replicas
// fallback-only state
__device__ float g_c[HIDDEN];
__device__ float g_partfb[NBLOCKS * VOCAB];
__device__ int   g_xi;

__device__ __forceinline__ float sigm(float x) { return 1.0f / (1.0f + expf(-x)); }

// ALL hot-path cross-block ops are RELAXED agent-scope (sc1 point ops at the
// MALL — no cache-maintenance storm; validated r6, 11.6x win). Ordering:
// vmcnt drain before arrive-RMW + real-time order at the coherence point.
#define LOAD_AG(p)     __hip_atomic_load((p), __ATOMIC_RELAXED, __HIP_MEMORY_SCOPE_AGENT)
#define STORE_AG(p, v) __hip_atomic_store((p), (v), __ATOMIC_RELAXED, __HIP_MEMORY_SCOPE_AGENT)
#define RMW_ADD_AG(p)  __hip_atomic_fetch_add((p), 1, __ATOMIC_RELAXED, __HIP_MEMORY_SCOPE_AGENT)
#define VM_DRAIN()     asm volatile("s_waitcnt vmcnt(0)" ::: "memory")
#define C_FENCE()      asm volatile("" ::: "memory")

// Load h[4m..4m+3] as two 8B relaxed agent loads (bypass stale L1/L2).
__device__ __forceinline__ float4 h_pair(const u64* h8, int m) {
    u64 lo = LOAD_AG((u64*)&h8[2 * m]);
    u64 hi = LOAD_AG((u64*)&h8[2 * m + 1]);
    float4 r;
    r.x = __uint_as_float((unsigned)lo);
    r.y = __uint_as_float((unsigned)(lo >> 32));
    r.z = __uint_as_float((unsigned)hi);
    r.w = __uint_as_float((unsigned)(hi >> 32));
    return r;
}

// Register-array select with compile-time indices only (no scratch).
__device__ __forceinline__ float sel7(const float w[VOCAB], int xi) {
    float r = w[0];
    #pragma unroll
    for (int v = 1; v < VOCAB; ++v) r = (xi == v) ? w[v] : r;
    return r;
}

// ---------------- cooperative single-dispatch kernel ----------------
__global__ __launch_bounds__(NTHREADS, 2)
void coop_kernel(const float* __restrict__ h0,  const float* __restrict__ c0,
                 const float* __restrict__ W_ih, const float* __restrict__ W_hh,
                 const float* __restrict__ b_ih, const float* __restrict__ b_hh,
                 const float* __restrict__ W_out, const float* __restrict__ b_out,
                 float* __restrict__ out)
{
    cg::grid_group grid = cg::this_grid();
    const int tid  = threadIdx.x;
    const int bx   = blockIdx.x;
    const int gid  = bx * NTHREADS + tid;
    const int lane = tid & 63;
    const int wib  = tid >> 6;
    const int j    = bx * NWAVES + wib;   // hidden unit, 0..2047

    const int leaf = bx >> 3;    // 0..63
    const int rep  = bx >> 6;    // replica 0..7

    __shared__ float s_part[NWAVES][VOCAB];
    __shared__ int   s_xi;

    // ---- per-launch init (replay-safe) ----
    if (gid < HIDDEN) STORE_AG(&g_h[0][gid], h0[gid]);
    if (bx == 0) {
        if (tid < NLEAF) STORE_AG(&g_c0[tid * 32], 0);
        if (tid == 0)    STORE_AG(&g_c2[0], 0);
        if (tid < 8)     { STORE_AG(&g_hgen[tid * 32], 0); STORE_AG(&g_xip[tid * 16], (u64)0); }
    }

    const float4* Wr0 = (const float4*)(W_hh + (size_t)j * HIDDEN);
    const float4* Wr1 = (const float4*)(W_hh + (size_t)(j + HIDDEN) * HIDDEN);
    const float4* Wr2 = (const float4*)(W_hh + (size_t)(j + 2 * HIDDEN) * HIDDEN);
    const float4* Wr3 = (const float4*)(W_hh + (size_t)(j + 3 * HIDDEN) * HIDDEN);

    float bsum0 = 0.f, bsum1 = 0.f, bsum2 = 0.f, bsum3 = 0.f;
    float cv = 0.f, h_fin = 0.f;
    float wih0[VOCAB], wih1[VOCAB], wih2[VOCAB], wih3[VOCAB];
    if (lane == 0) {
        bsum0 = b_ih[j]              + b_hh[j];
        bsum1 = b_ih[j + HIDDEN]     + b_hh[j + HIDDEN];
        bsum2 = b_ih[j + 2 * HIDDEN] + b_hh[j + 2 * HIDDEN];
        bsum3 = b_ih[j + 3 * HIDDEN] + b_hh[j + 3 * HIDDEN];
        cv = c0[j];    // c lives in a register all 1024 steps
        #pragma unroll
        for (int v = 0; v < VOCAB; ++v) {
            wih0[v] = W_ih[(size_t)j * VOCAB + v];
            wih1[v] = W_ih[(size_t)(j + HIDDEN) * VOCAB + v];
            wih2[v] = W_ih[(size_t)(j + 2 * HIDDEN) * VOCAB + v];
            wih3[v] = W_ih[(size_t)(j + 3 * HIDDEN) * VOCAB + v];
        }
    }
    const float wout = (lane < VOCAB) ? W_out[lane * HIDDEN + j] : 0.0f;
    float bov[VOCAB];
    #pragma unroll
    for (int v = 0; v < VOCAB; ++v) bov[v] = b_out[v];

    grid.sync();   // ONE cooperative barrier, init only

    int rb = 0, wbuf = 1;   // h buffer rotation (mod 3)

    for (int t = 0; t < STEPS; ++t) {
        // top spin: h(t) complete? (tid0-only + barrier broadcast — r8-proven)
        if (tid == 0) {
            int cur = LOAD_AG(&g_hgen[rep * 32]);
            while (cur < t) { __builtin_amdgcn_s_sleep(2); cur = LOAD_AG(&g_hgen[rep * 32]); }
        }
        C_FENCE();
        __syncthreads();

        const u64* h8 = (const u64*)g_h[rb];
        float4 hreg[8];
        #pragma unroll
        for (int it = 0; it < 8; ++it) hreg[it] = h_pair(h8, it * 64 + lane);

        float a0 = 0.f, a1 = 0.f, a2 = 0.f, a3 = 0.f;
        #pragma unroll
        for (int it = 0; it < 8; ++it) {
            const float4 hv = hreg[it];
            const float4 w0 = Wr0[it * 64 + lane];
            const float4 w1 = Wr1[it * 64 + lane];
            const float4 w2 = Wr2[it * 64 + lane];
            const float4 w3 = Wr3[it * 64 + lane];
            a0 += w0.x * hv.x + w0.y * hv.y + w0.z * hv.z + w0.w * hv.w;
            a1 += w1.x * hv.x + w1.y * hv.y + w1.z * hv.z + w1.w * hv.w;
            a2 += w2.x * hv.x + w2.y * hv.y + w2.z * hv.z + w2.w * hv.w;
            a3 += w3.x * hv.x + w3.y * hv.y + w3.z * hv.z + w3.w * hv.w;
        }
        #pragma unroll
        for (int off = 32; off > 0; off >>= 1) {
            a0 += __shfl_down(a0, off, 64);
            a1 += __shfl_down(a1, off, 64);
            a2 += __shfl_down(a2, off, 64);
            a3 += __shfl_down(a3, off, 64);
        }

        // xi(t): tagged t, published by step t-1's boss (in the GEMV's shadow).
        if (tid == 0) {
            int xi = VOCAB - 1;   // SOS at t=0
            if (t > 0) {
                u64 px = LOAD_AG(&g_xip[rep * 16]);
                while ((int)(unsigned)(px >> 32) < t) {
                    __builtin_amdgcn_s_sleep(1);
                    px = LOAD_AG(&g_xip[rep * 16]);
                }
                xi = (int)(unsigned)px;
            }
            s_xi = xi;
        }
        C_FENCE();
        __syncthreads();
        const int xi = s_xi;

        float h2v = 0.0f;
        if (lane == 0) {
            const float gi = a0 + bsum0 + sel7(wih0, xi);
            const float gf = a1 + bsum1 + sel7(wih1, xi);
            const float gg = a2 + bsum2 + sel7(wih2, xi);
            const float go = a3 + bsum3 + sel7(wih3, xi);
            cv  = sigm(gf) * cv + sigm(gi) * tanhf(gg);
            h2v = sigm(go) * tanhf(cv);
            h_fin = h2v;
            STORE_AG(&g_h[wbuf][j], h2v);   // relaxed sc1, lands at MALL
        }
        h2v = __shfl(h2v, 0, 64);

        if (lane < VOCAB) s_part[wib][lane] = h2v * wout;
        __syncthreads();   // drains each wave's vmcnt (h stores at MALL) + LDS visible

        // ---- count-first tree (wave 0): partials stored, then counting only ----
        if (wib == 0) {
            if (lane < VOCAB)
                STORE_AG(&g_pt[lane][bx],
                         s_part[0][lane] + s_part[1][lane] + s_part[2][lane] + s_part[3][lane]);
            VM_DRAIN();                     // partials + h at MALL before arrive
            int o0 = 0;
            if (lane == 0) o0 = RMW_ADD_AG(&g_c0[leaf * 32]);
            o0 = __shfl(o0, 0, 64);
            C_FENCE();
            if (o0 == (t + 1) * FAN - 1) {                 // leaf boss
                int o2 = 0;
                if (lane == 0) o2 = RMW_ADD_AG(&g_c2[0]);
                o2 = __shfl(o2, 0, 64);
                C_FENCE();
                if (o2 == (t + 1) * NLEAF - 1) {           // root boss (self-rotating)
                    // 1) unblock everyone FIRST
                    if (lane < 8) STORE_AG(&g_hgen[lane * 32], t + 1);
                    // 2) data work in the shadow: gather 512x7 partials (coalesced)
                    float l[VOCAB];
                    #pragma unroll
                    for (int v = 0; v < VOCAB; ++v) {
                        float s = 0.0f;
                        #pragma unroll
                        for (int k = 0; k < NBLOCKS / 64; ++k)
                            s += LOAD_AG(&g_pt[v][k * 64 + lane]);
                        #pragma unroll
                        for (int off = 32; off > 0; off >>= 1) s += __shfl_down(s, off, 64);
                        l[v] = s;
                    }
                    if (lane == 0) {
                        float mx = -1e30f;
                        #pragma unroll
                        for (int v = 0; v < VOCAB; ++v) { l[v] += bov[v]; mx = fmaxf(mx, l[v]); }
                        float se = 0.0f;
                        #pragma unroll
                        for (int v = 0; v < VOCAB; ++v) se += expf(l[v] - mx);
                        const float lse = mx + logf(se);
                        int am = 0; float best = l[0];
                        #pragma unroll
                        for (int v = 1; v < VOCAB; ++v) if (l[v] > best) { best = l[v]; am = v; }
                        #pragma unroll
                        for (int v = 0; v < VOCAB; ++v) out[t * VOCAB + v] = l[v] - lse;
                        const u64 val = ((u64)(unsigned)(t + 1) << 32) | (u64)(unsigned)am;
                        #pragma unroll
                        for (int r = 0; r < 8; ++r) STORE_AG(&g_xip[r * 16], val);
                    }
                }
            }
        }

        rb = wbuf;
        wbuf = (wbuf + 1 == 3) ? 0 : wbuf + 1;
    }

    // final state straight from registers
    if (lane == 0) {
        out[STEPS * VOCAB + j]          = h_fin;
        out[STEPS * VOCAB + HIDDEN + j] = cv;
    }
}

// ---------------- fallback: sequential per-step kernels (proven) ----------------
__global__ __launch_bounds__(NTHREADS)
void fb_init(const float* __restrict__ h0, const float* __restrict__ c0) {
    int gid = blockIdx.x * NTHREADS + threadIdx.x;
    if (gid < HIDDEN) { g_h[0][gid] = h0[gid]; g_c[gid] = c0[gid]; }
    if (gid == 0) g_xi = VOCAB - 1;
}

__global__ __launch_bounds__(NTHREADS, 2)
void fb_step(const float* __restrict__ W_ih, const float* __restrict__ W_hh,
             const float* __restrict__ b_ih, const float* __restrict__ b_hh,
             const float* __restrict__ W_out, int t)
{
    const int tid  = threadIdx.x;
    const int lane = tid & 63;
    const int wib  = tid >> 6;
    const int j    = blockIdx.x * NWAVES + wib;

    __shared__ float s_part[NWAVES][VOCAB];

    const float4* h4 = (const float4*)g_h[t & 1];
    const float4* Wr0 = (const float4*)(W_hh + (size_t)j * HIDDEN);
    const float4* Wr1 = (const float4*)(W_hh + (size_t)(j + HIDDEN) * HIDDEN);
    const float4* Wr2 = (const float4*)(W_hh + (size_t)(j + 2 * HIDDEN) * HIDDEN);
    const float4* Wr3 = (const float4*)(W_hh + (size_t)(j + 3 * HIDDEN) * HIDDEN);

    float a0 = 0.f, a1 = 0.f, a2 = 0.f, a3 = 0.f;
    #pragma unroll
    for (int it = 0; it < 8; ++it) {
        const float4 hv = h4[it * 64 + lane];
        const float4 w0 = Wr0[it * 64 + lane];
        const float4 w1 = Wr1[it * 64 + lane];
        const float4 w2 = Wr2[it * 64 + lane];
        const float4 w3 = Wr3[it * 64 + lane];
        a0 += w0.x * hv.x + w0.y * hv.y + w0.z * hv.z + w0.w * hv.w;
        a1 += w1.x * hv.x + w1.y * hv.y + w1.z * hv.z + w1.w * hv.w;
        a2 += w2.x * hv.x + w2.y * hv.y + w2.z * hv.z + w2.w * hv.w;
        a3 += w3.x * hv.x + w3.y * hv.y + w3.z * hv.z + w3.w * hv.w;
    }
    #pragma unroll
    for (int off = 32; off > 0; off >>= 1) {
        a0 += __shfl_down(a0, off, 64);
        a1 += __shfl_down(a1, off, 64);
        a2 += __shfl_down(a2, off, 64);
        a3 += __shfl_down(a3, off, 64);
    }

    float h2v = 0.0f;
    if (lane == 0) {
        const int xi = g_xi;
        const float gi = a0 + b_ih[j] + b_hh[j] + W_ih[j * VOCAB + xi];
        const float gf = a1 + b_ih[j + HIDDEN] + b_hh[j + HIDDEN] + W_ih[(j + HIDDEN) * VOCAB + xi];
        const float gg = a2 + b_ih[j + 2 * HIDDEN] + b_hh[j + 2 * HIDDEN] + W_ih[(j + 2 * HIDDEN) * VOCAB + xi];
        const float go = a3 + b_ih[j + 3 * HIDDEN] + b_hh[j + 3 * HIDDEN] + W_ih[(j + 3 * HIDDEN) * VOCAB + xi];
        const float cv = sigm(gf) * g_c[j] + sigm(gi) * tanhf(gg);
        h2v = sigm(go) * tanhf(cv);
        g_c[j] = cv;
        g_h[(t + 1) & 1][j] = h2v;
    }
    h2v = __shfl(h2v, 0, 64);

    const float wout = (lane < VOCAB) ? W_out[lane * HIDDEN + j] : 0.0f;
    if (lane < VOCAB) s_part[wib][lane] = h2v * wout;
    __syncthreads();
    if (tid < VOCAB)
        g_partfb[blockIdx.x * VOCAB + tid] =
            s_part[0][tid] + s_part[1][tid] + s_part[2][tid] + s_part[3][tid];
}

__global__ void fb_logits(const float* __restrict__ b_out, float* __restrict__ out, int t) {
    const int lane = threadIdx.x;   // 64 threads
    float lg[VOCAB];
    #pragma unroll
    for (int v = 0; v < VOCAB; ++v) {
        float s = 0.0f;
        for (int i = lane; i < NBLOCKS; i += 64) s += g_partfb[i * VOCAB + v];
        #pragma unroll
        for (int off = 32; off > 0; off >>= 1) s += __shfl_down(s, off, 64);
        lg[v] = s;
    }
    if (lane == 0) {
        float l[VOCAB];
        float mx = -1e30f;
        #pragma unroll
        for (int v = 0; v < VOCAB; ++v) { l[v] = lg[v] + b_out[v]; mx = fmaxf(mx, l[v]); }
        float se = 0.0f;
        #pragma unroll
        for (int v = 0; v < VOCAB; ++v) se += expf(l[v] - mx);
        const float lse = mx + logf(se);
        int am = 0; float best = l[0];
        #pragma unroll
        for (int v = 1; v < VOCAB; ++v) if (l[v] > best) { best = l[v]; am = v; }
        #pragma unroll
        for (int v = 0; v < VOCAB; ++v) out[t * VOCAB + v] = l[v] - lse;
        g_xi = am;
    }
}

__global__ __launch_bounds__(NTHREADS)
void fb_fin(float* __restrict__ out) {
    int gid = blockIdx.x * NTHREADS + threadIdx.x;
    if (gid < HIDDEN) {
        out[STEPS * VOCAB + gid]          = g_h[0][gid];
        out[STEPS * VOCAB + HIDDEN + gid] = g_c[gid];
    }
}

extern "C" void kernel_launch(void* const* d_in, const int* in_sizes, int n_in,
                              void* d_out, int out_size, void* d_ws, size_t ws_size,
                              hipStream_t stream)
{
    const float* h0    = (const float*)d_in[0];
    const float* c0    = (const float*)d_in[1];
    const float* W_ih  = (const float*)d_in[2];
    const float* W_hh  = (const float*)d_in[3];
    const float* b_ih  = (const float*)d_in[4];
    const float* b_hh  = (const float*)d_in[5];
    const float* W_out = (const float*)d_in[6];
    const float* b_out = (const float*)d_in[7];
    float* out = (float*)d_out;

    void* args[] = { &h0, &c0, &W_ih, &W_hh, &b_ih, &b_hh, &W_out, &b_out, &out };
    hipError_t e = hipLaunchCooperativeKernel((void*)coop_kernel,
                                              dim3(NBLOCKS), dim3(NTHREADS), args, 0, stream);
    if (e != hipSuccess) {
        fb_init<<<HIDDEN / NTHREADS, NTHREADS, 0, stream>>>(h0, c0);
        for (int t = 0; t < STEPS; ++t) {
            fb_step<<<NBLOCKS, NTHREADS, 0, stream>>>(W_ih, W_hh, b_ih, b_hh, W_out, t);
            fb_logits<<<1, 64, 0, stream>>>(b_out, out, t);
        }
        fb_fin<<<HIDDEN / NTHREADS, NTHREADS, 0, stream>>>(out);
    }
}

// Round 12
// 6987.824 us; speedup vs baseline: 2.4113x; 1.9398x over previous
//
#include <hip/hip_runtime.h>
#include <hip/hip_cooperative_groups.h>

namespace cg = cooperative_groups;

#define HIDDEN   2048
#define VOCAB    7
#define STEPS    1024
#define NBLOCKS  512
#define NTHREADS 256
#define NWAVES   (NTHREADS / 64)
#define FAN      8
#define NLEAF    (NBLOCKS / FAN)   // 64 leaves; root fan-in = 64

typedef unsigned long long u64;

// Cross-block state in device globals.  (r8-proven protocol layout.)
__device__ __align__(256) float g_h[3][HIDDEN];     // h triple-buffer
__device__ __align__(256) float g_p0[NLEAF][64];    // leaf partials: slot*7+v
__device__ __align__(256) float g_p1[NLEAF * 8];    // leaf-boss partials, stride 8
__device__ __align__(256) int   g_c0[NLEAF * 32];   // leaf counters, 128B apart
__device__ __align__(256) int   g_c2[32];           // root counter
__device__ __align__(256) u64   g_pub[8 * 16];      // publish replicas (gen<<32|xi)
// fallback-only state
__device__ float g_c[HIDDEN];
__device__ float g_partfb[NBLOCKS * VOCAB];
__device__ int   g_xi;

__device__ __forceinline__ float sigm(float x) { return 1.0f / (1.0f + expf(-x)); }

// ALL hot-path cross-block ops are RELAXED agent-scope (sc1 point ops at the
// MALL — no cache-maintenance storm; validated r6, 11.6x win). Ordering: vmcnt
// drain (via __syncthreads / VM_DRAIN) before arrive-RMW + real-time order at
// the single coherence point.
// PROTOCOL RULE (r10/r11 lesson): single end-of-loop publish of ONE word with
// data reduced BEFORE publish. Split publish / count-first exploded HBM 400x.
#define LOAD_AG(p)     __hip_atomic_load((p), __ATOMIC_RELAXED, __HIP_MEMORY_SCOPE_AGENT)
#define STORE_AG(p, v) __hip_atomic_store((p), (v), __ATOMIC_RELAXED, __HIP_MEMORY_SCOPE_AGENT)
#define RMW_ADD_AG(p)  __hip_atomic_fetch_add((p), 1, __ATOMIC_RELAXED, __HIP_MEMORY_SCOPE_AGENT)
#define VM_DRAIN()     asm volatile("s_waitcnt vmcnt(0)" ::: "memory")
#define C_FENCE()      asm volatile("" ::: "memory")

// Register-array select with compile-time indices only (no scratch).
__device__ __forceinline__ float sel7(const float w[VOCAB], int xi) {
    float r = w[0];
    #pragma unroll
    for (int v = 1; v < VOCAB; ++v) r = (xi == v) ? w[v] : r;
    return r;
}

// Sum 8 slots x 7 vocab held in lanes 0..55 (lane = slot*7+v) -> lanes 0..6.
__device__ __forceinline__ float slot_reduce(float x) {
    x += __shfl_down(x, 28, 64);
    x += __shfl_down(x, 14, 64);
    x += __shfl_down(x, 7, 64);
    return x;
}

// ---------------- cooperative single-dispatch kernel ----------------
__global__ __launch_bounds__(NTHREADS, 2)
void coop_kernel(const float* __restrict__ h0,  const float* __restrict__ c0,
                 const float* __restrict__ W_ih, const float* __restrict__ W_hh,
                 const float* __restrict__ b_ih, const float* __restrict__ b_hh,
                 const float* __restrict__ W_out, const float* __restrict__ b_out,
                 float* __restrict__ out)
{
    cg::grid_group grid = cg::this_grid();
    const int tid  = threadIdx.x;
    const int gid  = blockIdx.x * NTHREADS + tid;
    const int lane = tid & 63;
    const int wib  = tid >> 6;
    const int j    = blockIdx.x * NWAVES + wib;   // hidden unit, 0..2047

    const int leaf  = blockIdx.x >> 3;   // 0..63
    const int slot0 = blockIdx.x & 7;
    const int rep   = blockIdx.x >> 6;   // publish replica 0..7

    __shared__ u64   s_h8[HIDDEN / 2];   // 8 KB: h staged once per block
    __shared__ float s_part[NWAVES][VOCAB];
    __shared__ u64   s_gx;

    // ---- per-launch init (replay-safe) ----
    if (gid < HIDDEN) STORE_AG(&g_h[0][gid], h0[gid]);
    if (blockIdx.x == 0) {
        if (tid < NLEAF) STORE_AG(&g_c0[tid * 32], 0);
        if (tid == 0)    STORE_AG(&g_c2[0], 0);
        if (tid < 8)     STORE_AG(&g_pub[tid * 16], (u64)0);
    }

    const float4* Wr0 = (const float4*)(W_hh + (size_t)j * HIDDEN);
    const float4* Wr1 = (const float4*)(W_hh + (size_t)(j + HIDDEN) * HIDDEN);
    const float4* Wr2 = (const float4*)(W_hh + (size_t)(j + 2 * HIDDEN) * HIDDEN);
    const float4* Wr3 = (const float4*)(W_hh + (size_t)(j + 3 * HIDDEN) * HIDDEN);

    float bsum0 = 0.f, bsum1 = 0.f, bsum2 = 0.f, bsum3 = 0.f;
    float cv = 0.f, h_fin = 0.f;
    float wih0[VOCAB], wih1[VOCAB], wih2[VOCAB], wih3[VOCAB];
    if (lane == 0) {
        bsum0 = b_ih[j]              + b_hh[j];
        bsum1 = b_ih[j + HIDDEN]     + b_hh[j + HIDDEN];
        bsum2 = b_ih[j + 2 * HIDDEN] + b_hh[j + 2 * HIDDEN];
        bsum3 = b_ih[j + 3 * HIDDEN] + b_hh[j + 3 * HIDDEN];
        cv = c0[j];                               // c lives in a register all 1024 steps
        #pragma unroll
        for (int v = 0; v < VOCAB; ++v) {
            wih0[v] = W_ih[(size_t)j * VOCAB + v];
            wih1[v] = W_ih[(size_t)(j + HIDDEN) * VOCAB + v];
            wih2[v] = W_ih[(size_t)(j + 2 * HIDDEN) * VOCAB + v];
            wih3[v] = W_ih[(size_t)(j + 3 * HIDDEN) * VOCAB + v];
        }
    }
    const float wout = (lane < VOCAB) ? W_out[lane * HIDDEN + j] : 0.0f;
    float bov[VOCAB];
    #pragma unroll
    for (int v = 0; v < VOCAB; ++v) bov[v] = b_out[v];

    grid.sync();   // ONE cooperative barrier, init only

    int xi = VOCAB - 1;          // SOS
    int rb = 0, wbuf = 1;        // h buffer rotation (mod 3)

    for (int t = 0; t < STEPS; ++t) {
        // ---- stage h(t) into LDS once per block (4x fewer MALL reads) ----
        {
            const u64* h8 = (const u64*)g_h[rb];
            #pragma unroll
            for (int k = 0; k < 4; ++k)
                s_h8[k * 256 + tid] = LOAD_AG((u64*)&h8[k * 256 + tid]);
        }
        __syncthreads();

        const float4* s_h4 = (const float4*)s_h8;
        float4 hreg[8];
        #pragma unroll
        for (int it = 0; it < 8; ++it) hreg[it] = s_h4[it * 64 + lane];

        float a0 = 0.f, a1 = 0.f, a2 = 0.f, a3 = 0.f;
        #pragma unroll
        for (int it = 0; it < 8; ++it) {
            const float4 hv = hreg[it];
            const float4 w0 = Wr0[it * 64 + lane];
            const float4 w1 = Wr1[it * 64 + lane];
            const float4 w2 = Wr2[it * 64 + lane];
            const float4 w3 = Wr3[it * 64 + lane];
            a0 += w0.x * hv.x + w0.y * hv.y + w0.z * hv.z + w0.w * hv.w;
            a1 += w1.x * hv.x + w1.y * hv.y + w1.z * hv.z + w1.w * hv.w;
            a2 += w2.x * hv.x + w2.y * hv.y + w2.z * hv.z + w2.w * hv.w;
            a3 += w3.x * hv.x + w3.y * hv.y + w3.z * hv.z + w3.w * hv.w;
        }
        #pragma unroll
        for (int off = 32; off > 0; off >>= 1) {
            a0 += __shfl_down(a0, off, 64);
            a1 += __shfl_down(a1, off, 64);
            a2 += __shfl_down(a2, off, 64);
            a3 += __shfl_down(a3, off, 64);
        }

        float h2v = 0.0f;
        if (lane == 0) {
            const float gi = a0 + bsum0 + sel7(wih0, xi);
            const float gf = a1 + bsum1 + sel7(wih1, xi);
            const float gg = a2 + bsum2 + sel7(wih2, xi);
            const float go = a3 + bsum3 + sel7(wih3, xi);
            cv  = sigm(gf) * cv + sigm(gi) * tanhf(gg);
            h2v = sigm(go) * tanhf(cv);
            h_fin = h2v;
            STORE_AG(&g_h[wbuf][j], h2v);   // relaxed sc1, lands at MALL
        }
        h2v = __shfl(h2v, 0, 64);

        if (lane < VOCAB) s_part[wib][lane] = h2v * wout;
        __syncthreads();   // drains each wave's vmcnt (h stores at MALL) + LDS visible

        // ---- 2-level arrive/reduce tree (wave 0 only), all RELAXED — r8 verbatim ----
        if (wib == 0) {
            if (lane < VOCAB)
                STORE_AG(&g_p0[leaf][slot0 * VOCAB + lane],
                         s_part[0][lane] + s_part[1][lane] + s_part[2][lane] + s_part[3][lane]);
            VM_DRAIN();                     // partials at MALL before arrive
            int old0 = 0;
            if (lane == 0) old0 = RMW_ADD_AG(&g_c0[leaf * 32]);
            old0 = __shfl(old0, 0, 64);
            C_FENCE();
            if (old0 == (t + 1) * FAN - 1) {               // leaf boss
                float x = (lane < FAN * VOCAB) ? LOAD_AG(&g_p0[leaf][lane]) : 0.0f;
                x = slot_reduce(x);
                if (lane < VOCAB) STORE_AG(&g_p1[leaf * 8 + lane], x);
                VM_DRAIN();
                int old2 = 0;
                if (lane == 0) old2 = RMW_ADD_AG(&g_c2[0]);
                old2 = __shfl(old2, 0, 64);
                C_FENCE();
                if (old2 == (t + 1) * NLEAF - 1) {         // root boss
                    // reduce 64 leaf partials: lane l holds leaf l's value for each v
                    float l[VOCAB];
                    #pragma unroll
                    for (int v = 0; v < VOCAB; ++v) {
                        float s = LOAD_AG(&g_p1[lane * 8 + v]);
                        #pragma unroll
                        for (int off = 32; off > 0; off >>= 1) s += __shfl_down(s, off, 64);
                        l[v] = s;
                    }
                    if (lane == 0) {
                        float mx = -1e30f;
                        #pragma unroll
                        for (int v = 0; v < VOCAB; ++v) { l[v] += bov[v]; mx = fmaxf(mx, l[v]); }
                        float se = 0.0f;
                        #pragma unroll
                        for (int v = 0; v < VOCAB; ++v) se += expf(l[v] - mx);
                        const float lse = mx + logf(se);
                        int am = 0; float best = l[0];
                        #pragma unroll
                        for (int v = 1; v < VOCAB; ++v) if (l[v] > best) { best = l[v]; am = v; }
                        #pragma unroll
                        for (int v = 0; v < VOCAB; ++v) out[t * VOCAB + v] = l[v] - lse;
                        // SINGLE publish carries ALL inter-step data (gen|xi)
                        const u64 val = ((u64)(unsigned)(t + 1) << 32) | (u64)(unsigned)am;
                        #pragma unroll
                        for (int r = 0; r < 8; ++r) STORE_AG(&g_pub[r * 16], val);
                    }
                }
            }
        }

        // ---- single end-of-loop spin on this block's publish replica ----
        if (tid == 0) {
            u64 cur = LOAD_AG(&g_pub[rep * 16]);
            while ((unsigned)(cur >> 32) != (unsigned)(t + 1)) {
                __builtin_amdgcn_s_sleep(1);
                cur = LOAD_AG(&g_pub[rep * 16]);
            }
            s_gx = cur;
        }
        C_FENCE();
        __syncthreads();
        xi = (int)(unsigned)s_gx;

        rb = wbuf;
        wbuf = (wbuf + 1 == 3) ? 0 : wbuf + 1;
    }

    // final state straight from registers
    if (lane == 0) {
        out[STEPS * VOCAB + j]          = h_fin;
        out[STEPS * VOCAB + HIDDEN + j] = cv;
    }
}

// ---------------- fallback: sequential per-step kernels (proven) ----------------
__global__ __launch_bounds__(NTHREADS)
void fb_init(const float* __restrict__ h0, const float* __restrict__ c0) {
    int gid = blockIdx.x * NTHREADS + threadIdx.x;
    if (gid < HIDDEN) { g_h[0][gid] = h0[gid]; g_c[gid] = c0[gid]; }
    if (gid == 0) g_xi = VOCAB - 1;
}

__global__ __launch_bounds__(NTHREADS, 2)
void fb_step(const float* __restrict__ W_ih, const float* __restrict__ W_hh,
             const float* __restrict__ b_ih, const float* __restrict__ b_hh,
             const float* __restrict__ W_out, int t)
{
    const int tid  = threadIdx.x;
    const int lane = tid & 63;
    const int wib  = tid >> 6;
    const int j    = blockIdx.x * NWAVES + wib;

    __shared__ float s_part[NWAVES][VOCAB];

    const float4* h4 = (const float4*)g_h[t & 1];
    const float4* Wr0 = (const float4*)(W_hh + (size_t)j * HIDDEN);
    const float4* Wr1 = (const float4*)(W_hh + (size_t)(j + HIDDEN) * HIDDEN);
    const float4* Wr2 = (const float4*)(W_hh + (size_t)(j + 2 * HIDDEN) * HIDDEN);
    const float4* Wr3 = (const float4*)(W_hh + (size_t)(j + 3 * HIDDEN) * HIDDEN);

    float a0 = 0.f, a1 = 0.f, a2 = 0.f, a3 = 0.f;
    #pragma unroll
    for (int it = 0; it < 8; ++it) {
        const float4 hv = h4[it * 64 + lane];
        const float4 w0 = Wr0[it * 64 + lane];
        const float4 w1 = Wr1[it * 64 + lane];
        const float4 w2 = Wr2[it * 64 + lane];
        const float4 w3 = Wr3[it * 64 + lane];
        a0 += w0.x * hv.x + w0.y * hv.y + w0.z * hv.z + w0.w * hv.w;
        a1 += w1.x * hv.x + w1.y * hv.y + w1.z * hv.z + w1.w * hv.w;
        a2 += w2.x * hv.x + w2.y * hv.y + w2.z * hv.z + w2.w * hv.w;
        a3 += w3.x * hv.x + w3.y * hv.y + w3.z * hv.z + w3.w * hv.w;
    }
    #pragma unroll
    for (int off = 32; off > 0; off >>= 1) {
        a0 += __shfl_down(a0, off, 64);
        a1 += __shfl_down(a1, off, 64);
        a2 += __shfl_down(a2, off, 64);
        a3 += __shfl_down(a3, off, 64);
    }

    float h2v = 0.0f;
    if (lane == 0) {
        const int xi = g_xi;
        const float gi = a0 + b_ih[j] + b_hh[j] + W_ih[j * VOCAB + xi];
        const float gf = a1 + b_ih[j + HIDDEN] + b_hh[j + HIDDEN] + W_ih[(j + HIDDEN) * VOCAB + xi];
        const float gg = a2 + b_ih[j + 2 * HIDDEN] + b_hh[j + 2 * HIDDEN] + W_ih[(j + 2 * HIDDEN) * VOCAB + xi];
        const float go = a3 + b_ih[j + 3 * HIDDEN] + b_hh[j + 3 * HIDDEN] + W_ih[(j + 3 * HIDDEN) * VOCAB + xi];
        const float cv = sigm(gf) * g_c[j] + sigm(gi) * tanhf(gg);
        h2v = sigm(go) * tanhf(cv);
        g_c[j] = cv;
        g_h[(t + 1) & 1][j] = h2v;
    }
    h2v = __shfl(h2v, 0, 64);

    const float wout = (lane < VOCAB) ? W_out[lane * HIDDEN + j] : 0.0f;
    if (lane < VOCAB) s_part[wib][lane] = h2v * wout;
    __syncthreads();
    if (tid < VOCAB)
        g_partfb[blockIdx.x * VOCAB + tid] =
            s_part[0][tid] + s_part[1][tid] + s_part[2][tid] + s_part[3][tid];
}

__global__ void fb_logits(const float* __restrict__ b_out, float* __restrict__ out, int t) {
    const int lane = threadIdx.x;   // 64 threads
    float lg[VOCAB];
    #pragma unroll
    for (int v = 0; v < VOCAB; ++v) {
        float s = 0.0f;
        for (int i = lane; i < NBLOCKS; i += 64) s += g_partfb[i * VOCAB + v];
        #pragma unroll
        for (int off = 32; off > 0; off >>= 1) s += __shfl_down(s, off, 64);
        lg[v] = s;
    }
    if (lane == 0) {
        float l[VOCAB];
        float mx = -1e30f;
        #pragma unroll
        for (int v = 0; v < VOCAB; ++v) { l[v] = lg[v] + b_out[v]; mx = fmaxf(mx, l[v]); }
        float se = 0.0f;
        #pragma unroll
        for (int v = 0; v < VOCAB; ++v) se += expf(l[v] - mx);
        const float lse = mx + logf(se);
        int am = 0; float best = l[0];
        #pragma unroll
        for (int v = 1; v < VOCAB; ++v) if (l[v] > best) { best = l[v]; am = v; }
        #pragma unroll
        for (int v = 0; v < VOCAB; ++v) out[t * VOCAB + v] = l[v] - lse;
        g_xi = am;
    }
}

__global__ __launch_bounds__(NTHREADS)
void fb_fin(float* __restrict__ out) {
    int gid = blockIdx.x * NTHREADS + threadIdx.x;
    if (gid < HIDDEN) {
        out[STEPS * VOCAB + gid]          = g_h[0][gid];
        out[STEPS * VOCAB + HIDDEN + gid] = g_c[gid];
    }
}

extern "C" void kernel_launch(void* const* d_in, const int* in_sizes, int n_in,
                              void* d_out, int out_size, void* d_ws, size_t ws_size,
                              hipStream_t stream)
{
    const float* h0    = (const float*)d_in[0];
    const float* c0    = (const float*)d_in[1];
    const float* W_ih  = (const float*)d_in[2];
    const float* W_hh  = (const float*)d_in[3];
    const float* b_ih  = (const float*)d_in[4];
    const float* b_hh  = (const float*)d_in[5];
    const float* W_out = (const float*)d_in[6];
    const float* b_out = (const float*)d_in[7];
    float* out = (float*)d_out;

    void* args[] = { &h0, &c0, &W_ih, &W_hh, &b_ih, &b_hh, &W_out, &b_out, &out };
    hipError_t e = hipLaunchCooperativeKernel((void*)coop_kernel,
                                              dim3(NBLOCKS), dim3(NTHREADS), args, 0, stream);
    if (e != hipSuccess) {
        fb_init<<<HIDDEN / NTHREADS, NTHREADS, 0, stream>>>(h0, c0);
        for (int t = 0; t < STEPS; ++t) {
            fb_step<<<NBLOCKS, NTHREADS, 0, stream>>>(W_ih, W_hh, b_ih, b_hh, W_out, t);
            fb_logits<<<1, 64, 0, stream>>>(b_out, out, t);
        }
        fb_fin<<<HIDDEN / NTHREADS, NTHREADS, 0, stream>>>(out);
    }
}